// Round 2
// baseline (218.013 us; speedup 1.0000x reference)
//
#include <hip/hip_runtime.h>

typedef short bf16x8 __attribute__((ext_vector_type(8)));   // 8 bf16 in 4 VGPRs
typedef float f32x4  __attribute__((ext_vector_type(4)));
typedef float f32x2  __attribute__((ext_vector_type(2)));
typedef int   i32x4  __attribute__((ext_vector_type(4)));
typedef unsigned int u32x2 __attribute__((ext_vector_type(2)));

#define DEV static __device__ __forceinline__
#define LOG2E 1.4426950408889634f

DEV float bfu_to_f(unsigned short s) { return __builtin_bit_cast(float, (unsigned int)s << 16); }
DEV unsigned short f_to_bf(float f) {                 // RNE fp32 -> bf16
  unsigned int u = __builtin_bit_cast(unsigned int, f);
  u += 0x7fffu + ((u >> 16) & 1u);
  return (unsigned short)(u >> 16);
}
DEV unsigned int pack_bf_rne(float lo, float hi) {
  return (unsigned int)f_to_bf(lo) | ((unsigned int)f_to_bf(hi) << 16);
}
// bf16-pair unpack (lo/hi 16 bits of a u32 -> f32)
DEV float fplo(int u) { return __builtin_bit_cast(float, (unsigned int)u << 16); }
DEV float fphi(int u) { return __builtin_bit_cast(float, (unsigned int)u & 0xffff0000u); }
// guaranteed-native exp2 (single v_exp_f32)
DEV float nexp2(float x) {
#if __has_builtin(__builtin_amdgcn_exp2f)
  return __builtin_amdgcn_exp2f(x);
#else
  return exp2f(x);
#endif
}
// fp8 e4m3 pack/unpack (OCP on gfx950). Selector must be an ICE -> template param.
template<bool HI> DEV unsigned int pk_fp8(float a, float b, unsigned int old) {
  return __builtin_amdgcn_cvt_pk_fp8_f32(a, b, old, HI);
}
template<int W> DEV f32x2 upk_fp8(unsigned int w) {
  auto r = __builtin_amdgcn_cvt_pk_f32_fp8(w, W);
  f32x2 o; o[0] = r[0]; o[1] = r[1]; return o;
}

// dtype discriminator: adj[0][0] == 1.0 exactly. fp32 word0 == 0x3F800000;
// bf16 word0 low halfword = 0x3F80 != 0 -> never equal.
DEV bool detect_f32(const void* adj) { return ((const float*)adj)[0] == 1.0f; }

template<bool F32> DEV float ldS(const void* p, size_t i) {
  if constexpr (F32) return ((const float*)p)[i];
  else               return bfu_to_f(((const unsigned short*)p)[i]);
}
template<bool F32> DEV void ld8f(const void* p, size_t i, float* o) {
  if constexpr (F32) {
    const float* f = (const float*)p + i;
    f32x4 a = *(const f32x4*)f, b = *(const f32x4*)(f + 4);
    o[0]=a[0]; o[1]=a[1]; o[2]=a[2]; o[3]=a[3];
    o[4]=b[0]; o[5]=b[1]; o[6]=b[2]; o[7]=b[3];
  } else {
    i32x4 w = *(const i32x4*)((const unsigned short*)p + i);
#pragma unroll
    for (int k = 0; k < 4; ++k) {
      unsigned int u = (unsigned int)w[k];
      o[2*k]   = __builtin_bit_cast(float, u << 16);
      o[2*k+1] = __builtin_bit_cast(float, u & 0xffff0000u);
    }
  }
}
template<bool F32> DEV bf16x8 ldfrag(const void* p, size_t i) {
  if constexpr (F32) {
    float o[8]; ld8f<true>(p, i, o);
    union { bf16x8 v; unsigned short u[8]; } r;
#pragma unroll
    for (int k = 0; k < 8; ++k) r.u[k] = f_to_bf(o[k]);
    return r.v;
  } else {
    return __builtin_bit_cast(bf16x8, *(const i32x4*)((const unsigned short*)p + i));
  }
}

// ---------------- Kernel 0: adj -> fp8 e4m3 (handles fp32 or bf16 input) ----------
__global__ __launch_bounds__(256) void k_prep(const void* __restrict__ adj,
                                              unsigned char* __restrict__ adjf) {
  const size_t i0 = ((size_t)blockIdx.x * 256 + threadIdx.x) * 8;   // 4M elems total
  u32x2 o;
  if (detect_f32(adj)) {
    const float* a = (const float*)adj + i0;
    f32x4 v0 = *(const f32x4*)a, v1 = *(const f32x4*)(a + 4);
    o[0] = pk_fp8<true>(v0[2], v0[3], pk_fp8<false>(v0[0], v0[1], 0u));
    o[1] = pk_fp8<true>(v1[2], v1[3], pk_fp8<false>(v1[0], v1[1], 0u));
  } else {
    i32x4 w = *(const i32x4*)((const unsigned short*)adj + i0);
    float f[8];
#pragma unroll
    for (int k = 0; k < 4; ++k) {
      unsigned int u = (unsigned int)w[k];
      f[2*k]   = __builtin_bit_cast(float, u << 16);
      f[2*k+1] = __builtin_bit_cast(float, u & 0xffff0000u);
    }
    o[0] = pk_fp8<true>(f[2], f[3], pk_fp8<false>(f[0], f[1], 0u));
    o[1] = pk_fp8<true>(f[6], f[7], pk_fp8<false>(f[4], f[5], 0u));
  }
  *(u32x2*)(adjf + i0) = o;
}

// ---------------- Kernel 1: hT[(b*4+hh)*32+d][n] = (x@W^T) transposed, fp8 ----------
template<bool F32> DEV void k_h_body(const void* __restrict__ x, const void* __restrict__ W,
                                     unsigned char* __restrict__ hT,
                                     unsigned short (&t_s)[16][136]) {
  const int tid = threadIdx.x, lane = tid & 63, wave = tid >> 6;
  const int nt = blockIdx.x >> 3, ct = blockIdx.x & 7;    // 128 nt x 8 ct
  const int m = lane & 15, q = lane >> 4;
  bf16x8 wf[4];
#pragma unroll
  for (int k = 0; k < 4; ++k)
    wf[k] = ldfrag<F32>(W, (size_t)(ct * 16 + m) * 128 + q * 8 + k * 32);
#pragma unroll
  for (int s = 0; s < 2; ++s) {
    const int nsub = wave * 2 + s;
    const size_t xr = (size_t)(nt * 128 + nsub * 16 + m) * 128 + q * 8;
    f32x4 acc = {0.f, 0.f, 0.f, 0.f};
#pragma unroll
    for (int k = 0; k < 4; ++k)
      acc = __builtin_amdgcn_mfma_f32_16x16x32_bf16(ldfrag<F32>(x, xr + k * 32), wf[k],
                                                    acc, 0, 0, 0);
    u32x2 w2; w2[0] = pack_bf_rne(acc[0], acc[1]); w2[1] = pack_bf_rne(acc[2], acc[3]);
    *(u32x2*)&t_s[m][nsub * 16 + q * 4] = w2;
  }
  __syncthreads();
  const int row = tid >> 4, c8 = tid & 15;
  const int chg = ct * 16 + row, hh = chg >> 5, dloc = chg & 31;
  const int ng = nt * 128 + c8 * 8, b = ng >> 11, nl = ng & 2047;
  i32x4 v = *(const i32x4*)&t_s[row][c8 * 8];       // 8 bf16
  float f[8];
#pragma unroll
  for (int k = 0; k < 4; ++k) {
    unsigned int u = (unsigned int)v[k];
    f[2*k]   = __builtin_bit_cast(float, u << 16);
    f[2*k+1] = __builtin_bit_cast(float, u & 0xffff0000u);
  }
  u32x2 o;
  o[0] = pk_fp8<true>(f[2], f[3], pk_fp8<false>(f[0], f[1], 0u));
  o[1] = pk_fp8<true>(f[6], f[7], pk_fp8<false>(f[4], f[5], 0u));
  *(u32x2*)(hT + ((size_t)((b * 4 + hh) * 32 + dloc)) * 2048 + nl) = o;
}
__global__ __launch_bounds__(256) void k_h(const void* x, const void* W,
                                           unsigned char* hT, const void* adj) {
  __shared__ __align__(16) unsigned short t_s[16][136];   // shared across both instantiations
  if (detect_f32(adj)) k_h_body<true>(x, W, hT, t_s); else k_h_body<false>(x, W, hT, t_s);
}

// ---------------- Kernel 1b: src/dst projections -> rank-1 softmax factors ----------
// exp(leaky(s_i+d_j)) = max(exp(s+d), exp(0.2(s+d))); dividing the row by E_i=exp(s_i)
// (cancels in softmax) leaves p'_ij = adj * max(F_j, R_i*H_j) with
// R=exp(-0.8*src), F=exp(dst), H=exp(0.2*dst). F,H packed as one bf16 pair per j
// (lo=F, hi=H) -- bf16 rounding is far below the later fp8 quantization of p.
template<bool F32> DEV void k_sd_body(const unsigned char* __restrict__ hT,
                                      const void* __restrict__ a_src, const void* __restrict__ a_dst,
                                      float* __restrict__ rv, unsigned int* __restrict__ fhv) {
  const int t = blockIdx.x * 256 + threadIdx.x;      // (bh, n), n fastest
  const int n = t & 2047, bh = t >> 11, hh = bh & 3;
  const unsigned char* col = hT + (size_t)bh * 32 * 2048 + n;
  float s = 0.f, d = 0.f;
#pragma unroll
  for (int dd = 0; dd < 32; ++dd) {
    const float v = __builtin_amdgcn_cvt_f32_fp8((int)col[(size_t)dd * 2048], 0);
    s += v * ldS<F32>(a_src, hh * 32 + dd);
    d += v * ldS<F32>(a_dst, hh * 32 + dd);
  }
  rv[t] = nexp2(-0.8f * LOG2E * s);                  // R_i (f32)
  const float F = nexp2(LOG2E * d);                  // F_j
  const float H = nexp2(0.2f * LOG2E * d);           // H_j
  fhv[t] = pack_bf_rne(F, H);                        // lo=F, hi=H (bf16 pair)
}
__global__ __launch_bounds__(256) void k_sd(const unsigned char* hT, const void* a_src,
                                            const void* a_dst, float* rv, unsigned int* fhv,
                                            const void* adj) {
  if (detect_f32(adj)) k_sd_body<true>(hT, a_src, a_dst, rv, fhv);
  else                 k_sd_body<false>(hT, a_src, a_dst, rv, fhv);
}

// ---------------- Kernel 2: barrier-free all-global fp8 GAT attention ----------------
// Previous version was LDS-pipe-bound (~132 LDS cyc/wave/chunk x 32 waves/CU x 16
// chunks ~ 28 us on the one per-CU LDS pipe). All operands are small and L2-resident
// (adjf 4MB read 32x, hT 2MB read 64x, FH 8KB/bh), so: NO LDS staging, NO main-loop
// barriers. Each lane loads adj (8B), the two V^T MFMA A-operands (8B longs, used
// as-is), and packed-bf16 F/H straight from global, depth-1 register-prefetched.
// Block = 256 thr = 2 i-tiles x 2 j-halves (32 i-rows); grid = 32 bh x 64 i32.
// LDS only for the j-half merge epilogue (6 KB, one barrier).
struct PrefRegs {
  u32x2 aw[2];        // adj fp8, per jc
  long  a0[2], a1[2]; // V^T rows m, m+16 (MFMA A operands), per jc
  i32x4 fh0[2], fh1[2]; // packed bf16 F/H, 8 j's per jc
};

DEV void pref_load(PrefRegs& r, const unsigned char* ap, const unsigned char* vp0,
                   const unsigned char* vp1, const unsigned int* fp, int c) {
#pragma unroll
  for (int jc = 0; jc < 2; ++jc) {
    const int off = c * 128 + jc * 32;               // elements (1B adj/vt, 4B fh)
    r.aw[jc]  = *(const u32x2*)(ap + off);
    r.a0[jc]  = *(const long*)(vp0 + off);
    r.a1[jc]  = *(const long*)(vp1 + off);
    r.fh0[jc] = *(const i32x4*)(fp + off);
    r.fh1[jc] = *(const i32x4*)(fp + off + 4);
  }
}

DEV void attn_compute(const PrefRegs& r, const f32x2 Ri2,
                      f32x4& acc0, f32x4& acc1, f32x4& acc2) {
  const long Aones = 0x3838383838383838L;            // 8x fp8 e4m3 1.0
#pragma unroll
  for (int jc = 0; jc < 2; ++jc) {
    const u32x2 aw = r.aw[jc];
    f32x2 av0 = upk_fp8<0>(aw[0]), av1 = upk_fp8<1>(aw[0]);
    f32x2 av2 = upk_fp8<0>(aw[1]), av3 = upk_fp8<1>(aw[1]);
    const i32x4 u0 = r.fh0[jc], u1 = r.fh1[jc];
    f32x2 F0 = {fplo(u0[0]), fplo(u0[1])}, H0 = {fphi(u0[0]), fphi(u0[1])};
    f32x2 F1 = {fplo(u0[2]), fplo(u0[3])}, H1 = {fphi(u0[2]), fphi(u0[3])};
    f32x2 F2 = {fplo(u1[0]), fplo(u1[1])}, H2 = {fphi(u1[0]), fphi(u1[1])};
    f32x2 F3 = {fplo(u1[2]), fplo(u1[3])}, H3 = {fphi(u1[2]), fphi(u1[3])};
    f32x2 w0 = __builtin_elementwise_max(F0, Ri2 * H0);   // exp(leaky)/E_i (pk f32)
    f32x2 w1 = __builtin_elementwise_max(F1, Ri2 * H1);
    f32x2 w2 = __builtin_elementwise_max(F2, Ri2 * H2);
    f32x2 w3 = __builtin_elementwise_max(F3, Ri2 * H3);
    f32x2 pv0 = av0 * w0, pv1 = av1 * w1, pv2 = av2 * w2, pv3 = av3 * w3;
    u32x2 bp;
    bp[0] = pk_fp8<true>(pv1[0], pv1[1], pk_fp8<false>(pv0[0], pv0[1], 0u));
    bp[1] = pk_fp8<true>(pv3[0], pv3[1], pk_fp8<false>(pv2[0], pv2[1], 0u));
    const long B = __builtin_bit_cast(long, bp);
    acc0 = __builtin_amdgcn_mfma_f32_16x16x32_fp8_fp8(r.a0[jc], B, acc0, 0, 0, 0);
    acc1 = __builtin_amdgcn_mfma_f32_16x16x32_fp8_fp8(r.a1[jc], B, acc1, 0, 0, 0);
    acc2 = __builtin_amdgcn_mfma_f32_16x16x32_fp8_fp8(Aones,    B, acc2, 0, 0, 0);
  }
}

__global__ __launch_bounds__(256, 4) void k_attn(const unsigned char* __restrict__ adjf,
                                                 const unsigned char* __restrict__ hT,
                                                 const float* __restrict__ rv,
                                                 const unsigned int* __restrict__ fhv,
                                                 unsigned short* __restrict__ ao) {
  __shared__ __align__(16) float red[2 * 64 * 12];   // 6144 B epilogue scratch
  const int tid = threadIdx.x, lane = tid & 63, wave = tid >> 6;
  const int bh = blockIdx.x & 31, i32b = blockIdx.x >> 5;  // bh-fast: 32 blocks share adj
  const int b = bh >> 2, hh = bh & 3;
  const int m = lane & 15, q = lane >> 4;
  const int i0 = i32b * 32;
  const int itile = wave >> 1, jh = wave & 1;
  const int il = itile * 16 + m;                     // lane's local i-row (0..31)

  const unsigned char* ap  = adjf + (size_t)(i0 + il) * 2048 + jh * 64 + q * 8;
  const unsigned char* vp0 = hT + ((size_t)bh * 32 + m) * 2048 + jh * 64 + q * 8;
  const unsigned char* vp1 = vp0 + 16 * 2048;
  const unsigned int*  fp  = fhv + (size_t)bh * 2048 + jh * 64 + q * 8;

  const float Ri = rv[bh * 2048 + i0 + il];
  const f32x2 Ri2 = {Ri, Ri};
  f32x4 acc0 = {0.f,0.f,0.f,0.f}, acc1 = {0.f,0.f,0.f,0.f};
  f32x4 acc2 = {0.f,0.f,0.f,0.f};                    // den accumulator (ones-A MFMA)

  PrefRegs r[2];
  pref_load(r[0], ap, vp0, vp1, fp, 0);
#pragma unroll
  for (int c = 0; c < 16; ++c) {
    if (c < 15) pref_load(r[(c + 1) & 1], ap, vp0, vp1, fp, c + 1);
    attn_compute(r[c & 1], Ri2, acc0, acc1, acc2);
  }

  // ---- merge j-half partials via LDS, then write output ----
  const int ridx = (itile * 64 + lane) * 12;         // 48B stride: 16B-aligned stores
  if (jh == 1) {
    *(f32x4*)&red[ridx]     = acc0;
    *(f32x4*)&red[ridx + 4] = acc1;
    red[ridx + 8] = acc2[0];
  }
  __syncthreads();
  if (jh == 0) {
    acc0 += *(const f32x4*)&red[ridx];
    acc1 += *(const f32x4*)&red[ridx + 4];
    const float den = acc2[0] + red[ridx + 8];
    const float inv = 1.f / fmaxf(den, 1e-20f);
    // D: col = m = i, row = q*4+r = d. Lane writes channels q*4..+3 and 16+q*4..+3.
    unsigned short* op = ao + ((size_t)(b * 2048) + i0 + il) * 128 + hh * 32 + q * 4;
    u32x2 w0, w1;
    w0[0] = pack_bf_rne(acc0[0] * inv, acc0[1] * inv);
    w0[1] = pack_bf_rne(acc0[2] * inv, acc0[3] * inv);
    w1[0] = pack_bf_rne(acc1[0] * inv, acc1[1] * inv);
    w1[1] = pack_bf_rne(acc1[2] * inv, acc1[3] * inv);
    *(u32x2*)op        = w0;
    *(u32x2*)(op + 16) = w1;
  }
}

// ---------------- Kernel 3: y = LN(ao @ Wo^T + bo + x) ----------------
template<bool F32> DEV void k_out_body(const unsigned short* __restrict__ ao,
                                       const void* __restrict__ Wo, const void* __restrict__ bo,
                                       const void* __restrict__ x, const void* __restrict__ gamma,
                                       const void* __restrict__ beta, void* __restrict__ out,
                                       float (&y_s)[16][132]) {
  const int tid = threadIdx.x, lane = tid & 63, wave = tid >> 6;
  const int m = lane & 15, q = lane >> 4;
  const int rbase = blockIdx.x * 16;
  bf16x8 af[4];
#pragma unroll
  for (int k = 0; k < 4; ++k)
    af[k] = ldfrag<false>(ao, ((size_t)(rbase + m)) * 128 + q * 8 + k * 32);
  f32x4 acc[2] = {{0.f,0.f,0.f,0.f},{0.f,0.f,0.f,0.f}};
#pragma unroll
  for (int ct = 0; ct < 2; ++ct) {
    const size_t wrow = (size_t)(wave * 32 + ct * 16 + m) * 128 + q * 8;
#pragma unroll
    for (int k = 0; k < 4; ++k)
      acc[ct] = __builtin_amdgcn_mfma_f32_16x16x32_bf16(af[k], ldfrag<F32>(Wo, wrow + k * 32),
                                                        acc[ct], 0, 0, 0);
  }
#pragma unroll
  for (int ct = 0; ct < 2; ++ct) {
    const int c = wave * 32 + ct * 16 + m;
    const float bov = ldS<F32>(bo, c);
#pragma unroll
    for (int r = 0; r < 4; ++r) {
      const int row = q * 4 + r;
      y_s[row][c] = acc[ct][r] + bov + ldS<F32>(x, (size_t)(rbase + row) * 128 + c);
    }
  }
  __syncthreads();
  const int r = tid >> 4, c16 = tid & 15;
  float vals[8], sum = 0.f, sq = 0.f;
#pragma unroll
  for (int k = 0; k < 8; ++k) {
    const float v = y_s[r][c16 * 8 + k];
    vals[k] = v; sum += v; sq += v * v;
  }
#pragma unroll
  for (int msk = 1; msk < 16; msk <<= 1) {
    sum += __shfl_xor(sum, msk, 16);
    sq  += __shfl_xor(sq,  msk, 16);
  }
  const float mu  = sum * (1.f / 128.f);
  const float var = fmaxf(sq * (1.f / 128.f) - mu * mu, 0.f);
  const float rstd = rsqrtf(var + 1e-5f);
  float o[8];
#pragma unroll
  for (int k = 0; k < 8; ++k) {
    const int c = c16 * 8 + k;
    o[k] = (vals[k] - mu) * rstd * ldS<F32>(gamma, c) + ldS<F32>(beta, c);
  }
  const size_t obase = (size_t)(rbase + r) * 128 + c16 * 8;
  if constexpr (F32) {
    float* op = (float*)out + obase;
    f32x4 w0 = {o[0],o[1],o[2],o[3]}, w1 = {o[4],o[5],o[6],o[7]};
    *(f32x4*)op = w0; *(f32x4*)(op + 4) = w1;
  } else {
    union { unsigned short u[8]; i32x4 v; } ob;
#pragma unroll
    for (int k = 0; k < 8; ++k) ob.u[k] = f_to_bf(o[k]);
    *(i32x4*)((unsigned short*)out + obase) = ob.v;
  }
}
__global__ __launch_bounds__(256) void k_out(const unsigned short* ao, const void* Wo,
                                             const void* bo, const void* x, const void* gamma,
                                             const void* beta, void* out, const void* adj) {
  __shared__ __align__(16) float y_s[16][132];   // shared across both instantiations
  if (detect_f32(adj)) k_out_body<true>(ao, Wo, bo, x, gamma, beta, out, y_s);
  else                 k_out_body<false>(ao, Wo, bo, x, gamma, beta, out, y_s);
}

// ---------------- launch ----------------
extern "C" void kernel_launch(void* const* d_in, const int* in_sizes, int n_in,
                              void* d_out, int out_size, void* d_ws, size_t ws_size,
                              hipStream_t stream) {
  const void* x     = d_in[0];
  const void* adj   = d_in[1];
  const void* W     = d_in[2];
  const void* a_src = d_in[3];
  const void* a_dst = d_in[4];
  const void* Wo    = d_in[5];
  const void* bo    = d_in[6];
  const void* gamma = d_in[7];
  const void* beta  = d_in[8];

  char* ws = (char*)d_ws;
  unsigned char*  hT_ws  = (unsigned char*)ws;               // 2,097,152 B  fp8 hT (BH*32, N)
  unsigned short* ao_ws  = (unsigned short*)(ws + 2097152);  // 4,194,304 B  bf16 attn out
  float*          rv_ws  = (float*)(ws + 6291456);           // 262,144 B    fp32 R=exp(-.8 src)
  unsigned int*   fh_ws  = (unsigned int*)(ws + 6553600);    // 262,144 B    packed bf16 F,H
  unsigned char*  adjf   = (unsigned char*)(ws + 6815744);   // 4,194,304 B  fp8 adj
                                                             // total 11,010,048 B

  k_prep<<<2048, 256, 0, stream>>>(adj, adjf);
  k_h   <<<1024, 256, 0, stream>>>(x, W, hT_ws, adj);
  k_sd  <<<256,  256, 0, stream>>>(hT_ws, a_src, a_dst, rv_ws, fh_ws, adj);
  k_attn<<<2048, 256, 0, stream>>>(adjf, hT_ws, rv_ws, fh_ws, ao_ws);
  k_out <<<1024, 256, 0, stream>>>(ao_ws, Wo, bo, x, gamma, beta, d_out, adj);
}

// Round 3
// 146.352 us; speedup vs baseline: 1.4897x; 1.4897x over previous
//
#include <hip/hip_runtime.h>

typedef short bf16x8 __attribute__((ext_vector_type(8)));   // 8 bf16 in 4 VGPRs
typedef float f32x4  __attribute__((ext_vector_type(4)));
typedef float f32x2  __attribute__((ext_vector_type(2)));
typedef int   i32x4  __attribute__((ext_vector_type(4)));
typedef unsigned int u32x2 __attribute__((ext_vector_type(2)));

#define DEV static __device__ __forceinline__
#define LOG2E 1.4426950408889634f

DEV float bfu_to_f(unsigned short s) { return __builtin_bit_cast(float, (unsigned int)s << 16); }
DEV unsigned short f_to_bf(float f) {                 // RNE fp32 -> bf16
  unsigned int u = __builtin_bit_cast(unsigned int, f);
  u += 0x7fffu + ((u >> 16) & 1u);
  return (unsigned short)(u >> 16);
}
DEV unsigned int pack_bf_rne(float lo, float hi) {
  return (unsigned int)f_to_bf(lo) | ((unsigned int)f_to_bf(hi) << 16);
}
// bf16-pair unpack (lo/hi 16 bits of a u32 -> f32)
DEV float fplo(int u) { return __builtin_bit_cast(float, (unsigned int)u << 16); }
DEV float fphi(int u) { return __builtin_bit_cast(float, (unsigned int)u & 0xffff0000u); }
// guaranteed-native exp2 (single v_exp_f32)
DEV float nexp2(float x) {
#if __has_builtin(__builtin_amdgcn_exp2f)
  return __builtin_amdgcn_exp2f(x);
#else
  return exp2f(x);
#endif
}
// fp8 e4m3 pack/unpack (OCP on gfx950). Selector must be an ICE -> template param.
template<bool HI> DEV unsigned int pk_fp8(float a, float b, unsigned int old) {
  return __builtin_amdgcn_cvt_pk_fp8_f32(a, b, old, HI);
}
template<int W> DEV f32x2 upk_fp8(unsigned int w) {
  auto r = __builtin_amdgcn_cvt_pk_f32_fp8(w, W);
  f32x2 o; o[0] = r[0]; o[1] = r[1]; return o;
}

// dtype discriminator: adj[0][0] == 1.0 exactly. fp32 word0 == 0x3F800000;
// bf16 word0 low halfword = 0x3F80 != 0 -> never equal.
DEV bool detect_f32(const void* adj) { return ((const float*)adj)[0] == 1.0f; }

template<bool F32> DEV float ldS(const void* p, size_t i) {
  if constexpr (F32) return ((const float*)p)[i];
  else               return bfu_to_f(((const unsigned short*)p)[i]);
}
template<bool F32> DEV void ld8f(const void* p, size_t i, float* o) {
  if constexpr (F32) {
    const float* f = (const float*)p + i;
    f32x4 a = *(const f32x4*)f, b = *(const f32x4*)(f + 4);
    o[0]=a[0]; o[1]=a[1]; o[2]=a[2]; o[3]=a[3];
    o[4]=b[0]; o[5]=b[1]; o[6]=b[2]; o[7]=b[3];
  } else {
    i32x4 w = *(const i32x4*)((const unsigned short*)p + i);
#pragma unroll
    for (int k = 0; k < 4; ++k) {
      unsigned int u = (unsigned int)w[k];
      o[2*k]   = __builtin_bit_cast(float, u << 16);
      o[2*k+1] = __builtin_bit_cast(float, u & 0xffff0000u);
    }
  }
}
template<bool F32> DEV bf16x8 ldfrag(const void* p, size_t i) {
  if constexpr (F32) {
    float o[8]; ld8f<true>(p, i, o);
    union { bf16x8 v; unsigned short u[8]; } r;
#pragma unroll
    for (int k = 0; k < 8; ++k) r.u[k] = f_to_bf(o[k]);
    return r.v;
  } else {
    return __builtin_bit_cast(bf16x8, *(const i32x4*)((const unsigned short*)p + i));
  }
}

// ---------------- Kernel 0: adj -> fp8 e4m3 (handles fp32 or bf16 input) ----------
__global__ __launch_bounds__(256) void k_prep(const void* __restrict__ adj,
                                              unsigned char* __restrict__ adjf) {
  const size_t i0 = ((size_t)blockIdx.x * 256 + threadIdx.x) * 8;   // 4M elems total
  u32x2 o;
  if (detect_f32(adj)) {
    const float* a = (const float*)adj + i0;
    f32x4 v0 = *(const f32x4*)a, v1 = *(const f32x4*)(a + 4);
    o[0] = pk_fp8<true>(v0[2], v0[3], pk_fp8<false>(v0[0], v0[1], 0u));
    o[1] = pk_fp8<true>(v1[2], v1[3], pk_fp8<false>(v1[0], v1[1], 0u));
  } else {
    i32x4 w = *(const i32x4*)((const unsigned short*)adj + i0);
    float f[8];
#pragma unroll
    for (int k = 0; k < 4; ++k) {
      unsigned int u = (unsigned int)w[k];
      f[2*k]   = __builtin_bit_cast(float, u << 16);
      f[2*k+1] = __builtin_bit_cast(float, u & 0xffff0000u);
    }
    o[0] = pk_fp8<true>(f[2], f[3], pk_fp8<false>(f[0], f[1], 0u));
    o[1] = pk_fp8<true>(f[6], f[7], pk_fp8<false>(f[4], f[5], 0u));
  }
  *(u32x2*)(adjf + i0) = o;
}

// ---------------- Kernel 1: hT[(b*4+hh)*32+d][n] = (x@W^T) transposed, fp8 ----------
template<bool F32> DEV void k_h_body(const void* __restrict__ x, const void* __restrict__ W,
                                     unsigned char* __restrict__ hT,
                                     unsigned short (&t_s)[16][136]) {
  const int tid = threadIdx.x, lane = tid & 63, wave = tid >> 6;
  const int nt = blockIdx.x >> 3, ct = blockIdx.x & 7;    // 128 nt x 8 ct
  const int m = lane & 15, q = lane >> 4;
  bf16x8 wf[4];
#pragma unroll
  for (int k = 0; k < 4; ++k)
    wf[k] = ldfrag<F32>(W, (size_t)(ct * 16 + m) * 128 + q * 8 + k * 32);
#pragma unroll
  for (int s = 0; s < 2; ++s) {
    const int nsub = wave * 2 + s;
    const size_t xr = (size_t)(nt * 128 + nsub * 16 + m) * 128 + q * 8;
    f32x4 acc = {0.f, 0.f, 0.f, 0.f};
#pragma unroll
    for (int k = 0; k < 4; ++k)
      acc = __builtin_amdgcn_mfma_f32_16x16x32_bf16(ldfrag<F32>(x, xr + k * 32), wf[k],
                                                    acc, 0, 0, 0);
    u32x2 w2; w2[0] = pack_bf_rne(acc[0], acc[1]); w2[1] = pack_bf_rne(acc[2], acc[3]);
    *(u32x2*)&t_s[m][nsub * 16 + q * 4] = w2;
  }
  __syncthreads();
  const int row = tid >> 4, c8 = tid & 15;
  const int chg = ct * 16 + row, hh = chg >> 5, dloc = chg & 31;
  const int ng = nt * 128 + c8 * 8, b = ng >> 11, nl = ng & 2047;
  i32x4 v = *(const i32x4*)&t_s[row][c8 * 8];       // 8 bf16
  float f[8];
#pragma unroll
  for (int k = 0; k < 4; ++k) {
    unsigned int u = (unsigned int)v[k];
    f[2*k]   = __builtin_bit_cast(float, u << 16);
    f[2*k+1] = __builtin_bit_cast(float, u & 0xffff0000u);
  }
  u32x2 o;
  o[0] = pk_fp8<true>(f[2], f[3], pk_fp8<false>(f[0], f[1], 0u));
  o[1] = pk_fp8<true>(f[6], f[7], pk_fp8<false>(f[4], f[5], 0u));
  *(u32x2*)(hT + ((size_t)((b * 4 + hh) * 32 + dloc)) * 2048 + nl) = o;
}
__global__ __launch_bounds__(256) void k_h(const void* x, const void* W,
                                           unsigned char* hT, const void* adj) {
  __shared__ __align__(16) unsigned short t_s[16][136];   // shared across both instantiations
  if (detect_f32(adj)) k_h_body<true>(x, W, hT, t_s); else k_h_body<false>(x, W, hT, t_s);
}

// ---------------- Kernel 1b: src/dst projections -> rank-1 softmax factors ----------
// exp(leaky(s_i+d_j)) = max(exp(s+d), exp(0.2(s+d))); dividing the row by E_i=exp(s_i)
// (cancels in softmax) leaves p'_ij = adj * max(F_j, R_i*H_j) with
// R=exp(-0.8*src), F=exp(dst), H=exp(0.2*dst). F,H packed as one bf16 pair per j
// (lo=F, hi=H) -- bf16 rounding is far below the later fp8 quantization of p.
template<bool F32> DEV void k_sd_body(const unsigned char* __restrict__ hT,
                                      const void* __restrict__ a_src, const void* __restrict__ a_dst,
                                      float* __restrict__ rv, unsigned int* __restrict__ fhv) {
  const int t = blockIdx.x * 256 + threadIdx.x;      // (bh, n), n fastest
  const int n = t & 2047, bh = t >> 11, hh = bh & 3;
  const unsigned char* col = hT + (size_t)bh * 32 * 2048 + n;
  float s = 0.f, d = 0.f;
#pragma unroll
  for (int dd = 0; dd < 32; ++dd) {
    const float v = __builtin_amdgcn_cvt_f32_fp8((int)col[(size_t)dd * 2048], 0);
    s += v * ldS<F32>(a_src, hh * 32 + dd);
    d += v * ldS<F32>(a_dst, hh * 32 + dd);
  }
  rv[t] = nexp2(-0.8f * LOG2E * s);                  // R_i (f32)
  const float F = nexp2(LOG2E * d);                  // F_j
  const float H = nexp2(0.2f * LOG2E * d);           // H_j
  fhv[t] = pack_bf_rne(F, H);                        // lo=F, hi=H (bf16 pair)
}
__global__ __launch_bounds__(256) void k_sd(const unsigned char* hT, const void* a_src,
                                            const void* a_dst, float* rv, unsigned int* fhv,
                                            const void* adj) {
  if (detect_f32(adj)) k_sd_body<true>(hT, a_src, a_dst, rv, fhv);
  else                 k_sd_body<false>(hT, a_src, a_dst, rv, fhv);
}

// ---------------- Kernel 2: LDS-staged fp8 GAT attention, 64 i-rows per wave --------
// Round-2's all-global version was gather-bound (16 distinct cache lines per load).
// Back to LDS staging (coalesced global reads, LDS does the scatter), but with the
// vt/FH reads amortized 4x: each wave owns 4 i-tiles (64 rows), so the
// itile-independent A-operands (vt) and F/H are read from LDS once per jc and feed
// 4 MFMA-tiles. F/H bf16-packed halves their LDS cost. Block = 256 thr = 4 waves =
// 2 i-groups(64 i) x 2 j-halves -> 128 i/block; grid = 32 bh x 16 = 512 (2 blocks/CU,
// 8 waves/CU). Double-buffered LDS, reg-prefetch, ONE barrier per 128-j chunk.
// Est. per-CU-chunk: LDS ~1400 cyc > VALU ~700 -> ~9.5 us LDS-bound floor.
struct SmemAttn {
  unsigned char adj[2][128][144];  // 36864 B [buf][i-local][j] (stride 144: 2-way=free)
  unsigned char vt[2][32][144];    //  9216 B [buf][d][j]
  unsigned int  fh[2][128];        //  1024 B [buf][j] packed bf16 (F,H)
};                                 // 47104 B -> 2 blocks/CU by grid, 3 by LDS

__global__ __launch_bounds__(256, 2) void k_attn(const unsigned char* __restrict__ adjf,
                                                 const unsigned char* __restrict__ hT,
                                                 const float* __restrict__ rv,
                                                 const unsigned int* __restrict__ fhv,
                                                 unsigned short* __restrict__ ao) {
  __shared__ __align__(16) SmemAttn sm;
  const int tid = threadIdx.x, lane = tid & 63, wave = tid >> 6;
  const int bh = blockIdx.x & 31, iblk = blockIdx.x >> 5;  // bh-fast: share adj in L2
  const int b = bh >> 2, hh = bh & 3;
  const int m = lane & 15, q = lane >> 4;
  const int ig = wave >> 1, jh = wave & 1;
  const int i0 = iblk * 128;

  // staging maps (256 threads)
  const int ar = tid >> 1, ac = (tid & 1) * 64;      // adj: 128 rows x 2 thr x 64 B
  const int vr = tid >> 3, vc = (tid & 7) * 16;      // vt: 32 rows x 8 thr x 16 B
  const bool fstg = tid < 32;                        // fh: 32 thr x 16 B

  const unsigned char* ap = adjf + (size_t)(i0 + ar) * 2048 + ac;
  const unsigned char* vp = hT + ((size_t)bh * 32 + vr) * 2048 + vc;
  const unsigned int*  fp = fhv + (size_t)bh * 2048 + tid * 4;

  i32x4 arr0, arr1, arr2, arr3, vrr, frr;

  // ---- prologue: stage chunk 0 into buf 0 ----
  arr0 = *(const i32x4*)(ap);      arr1 = *(const i32x4*)(ap + 16);
  arr2 = *(const i32x4*)(ap + 32); arr3 = *(const i32x4*)(ap + 48);
  vrr = *(const i32x4*)vp;
  if (fstg) frr = *(const i32x4*)fp;
  *(i32x4*)&sm.adj[0][ar][ac]      = arr0;
  *(i32x4*)&sm.adj[0][ar][ac + 16] = arr1;
  *(i32x4*)&sm.adj[0][ar][ac + 32] = arr2;
  *(i32x4*)&sm.adj[0][ar][ac + 48] = arr3;
  *(i32x4*)&sm.vt[0][vr][vc] = vrr;
  if (fstg) *(i32x4*)&sm.fh[0][tid * 4] = frr;
  __syncthreads();

  float Riv[4];
#pragma unroll
  for (int it = 0; it < 4; ++it)
    Riv[it] = rv[bh * 2048 + i0 + ig * 64 + it * 16 + m];

  f32x4 accA[4], accB[4], accD[4];
#pragma unroll
  for (int it = 0; it < 4; ++it) {
    accA[it] = f32x4{0.f,0.f,0.f,0.f};
    accB[it] = f32x4{0.f,0.f,0.f,0.f};
    accD[it] = f32x4{0.f,0.f,0.f,0.f};
  }
  const long Aones = 0x3838383838383838L;            // 8x fp8 e4m3 1.0

#pragma unroll 2
  for (int c = 0; c < 16; ++c) {
    const int cb = c & 1;
    if (c < 15) {                                    // issue chunk c+1 loads (coalesced)
      const int o = (c + 1) * 128;
      arr0 = *(const i32x4*)(ap + o);      arr1 = *(const i32x4*)(ap + o + 16);
      arr2 = *(const i32x4*)(ap + o + 32); arr3 = *(const i32x4*)(ap + o + 48);
      vrr = *(const i32x4*)(vp + o);
      if (fstg) frr = *(const i32x4*)(fp + o);
    }
    // ---- compute: this wave's j-half on buf cb; vt/FH read once, reused by 4 itiles
#pragma unroll
    for (int jc = 0; jc < 2; ++jc) {
      const int jq = jh * 64 + jc * 32 + q * 8;
      const long A0 = *(const long*)&sm.vt[cb][m][jq];        // V^T row d=m
      const long A1 = *(const long*)&sm.vt[cb][16 + m][jq];   // d=m+16
      const i32x4 u0 = *(const i32x4*)&sm.fh[cb][jq];
      const i32x4 u1 = *(const i32x4*)&sm.fh[cb][jq + 4];
      f32x2 F0 = {fplo(u0[0]), fplo(u0[1])}, H0 = {fphi(u0[0]), fphi(u0[1])};
      f32x2 F1 = {fplo(u0[2]), fplo(u0[3])}, H1 = {fphi(u0[2]), fphi(u0[3])};
      f32x2 F2 = {fplo(u1[0]), fplo(u1[1])}, H2 = {fphi(u1[0]), fphi(u1[1])};
      f32x2 F3 = {fplo(u1[2]), fplo(u1[3])}, H3 = {fphi(u1[2]), fphi(u1[3])};
#pragma unroll
      for (int it = 0; it < 4; ++it) {
        const int il = ig * 64 + it * 16 + m;
        const u32x2 aw = *(const u32x2*)&sm.adj[cb][il][jq];  // 8 fp8
        f32x2 av0 = upk_fp8<0>(aw[0]), av1 = upk_fp8<1>(aw[0]);
        f32x2 av2 = upk_fp8<0>(aw[1]), av3 = upk_fp8<1>(aw[1]);
        const f32x2 Ri2 = {Riv[it], Riv[it]};
        f32x2 w0 = __builtin_elementwise_max(F0, Ri2 * H0);   // exp(leaky)/E_i (pk)
        f32x2 w1 = __builtin_elementwise_max(F1, Ri2 * H1);
        f32x2 w2 = __builtin_elementwise_max(F2, Ri2 * H2);
        f32x2 w3 = __builtin_elementwise_max(F3, Ri2 * H3);
        f32x2 pv0 = av0 * w0, pv1 = av1 * w1, pv2 = av2 * w2, pv3 = av3 * w3;
        u32x2 bp;
        bp[0] = pk_fp8<true>(pv1[0], pv1[1], pk_fp8<false>(pv0[0], pv0[1], 0u));
        bp[1] = pk_fp8<true>(pv3[0], pv3[1], pk_fp8<false>(pv2[0], pv2[1], 0u));
        const long B = __builtin_bit_cast(long, bp);
        accA[it] = __builtin_amdgcn_mfma_f32_16x16x32_fp8_fp8(A0,    B, accA[it], 0, 0, 0);
        accB[it] = __builtin_amdgcn_mfma_f32_16x16x32_fp8_fp8(A1,    B, accB[it], 0, 0, 0);
        accD[it] = __builtin_amdgcn_mfma_f32_16x16x32_fp8_fp8(Aones, B, accD[it], 0, 0, 0);
      }
    }
    if (c < 15) {                                    // write chunk c+1 into other buffer
      const int nb = cb ^ 1;
      *(i32x4*)&sm.adj[nb][ar][ac]      = arr0;
      *(i32x4*)&sm.adj[nb][ar][ac + 16] = arr1;
      *(i32x4*)&sm.adj[nb][ar][ac + 32] = arr2;
      *(i32x4*)&sm.adj[nb][ar][ac + 48] = arr3;
      *(i32x4*)&sm.vt[nb][vr][vc] = vrr;
      if (fstg) *(i32x4*)&sm.fh[nb][tid * 4] = frr;
    }
    __syncthreads();
  }

  // ---- merge j-half partials via LDS (reuse sm), then write output ----
  float* red = (float*)&sm;                          // 512 slots x 12 f32 = 24576 B
  if (jh == 1) {
#pragma unroll
    for (int it = 0; it < 4; ++it) {
      const int base = ((ig * 4 + it) * 64 + lane) * 12;
      *(f32x4*)&red[base]     = accA[it];
      *(f32x4*)&red[base + 4] = accB[it];
      red[base + 8] = accD[it][0];
    }
  }
  __syncthreads();
  if (jh == 0) {
#pragma unroll
    for (int it = 0; it < 4; ++it) {
      const int base = ((ig * 4 + it) * 64 + lane) * 12;
      const f32x4 a0 = accA[it] + *(const f32x4*)&red[base];
      const f32x4 a1 = accB[it] + *(const f32x4*)&red[base + 4];
      const float den = accD[it][0] + red[base + 8];
      const float inv = 1.f / fmaxf(den, 1e-20f);
      const int il = ig * 64 + it * 16 + m;
      // D: col = m = i, row = q*4+r = d. Lane writes channels q*4..+3 and 16+q*4..+3.
      unsigned short* op = ao + ((size_t)(b * 2048) + i0 + il) * 128 + hh * 32 + q * 4;
      u32x2 w0, w1;
      w0[0] = pack_bf_rne(a0[0] * inv, a0[1] * inv);
      w0[1] = pack_bf_rne(a0[2] * inv, a0[3] * inv);
      w1[0] = pack_bf_rne(a1[0] * inv, a1[1] * inv);
      w1[1] = pack_bf_rne(a1[2] * inv, a1[3] * inv);
      *(u32x2*)op        = w0;
      *(u32x2*)(op + 16) = w1;
    }
  }
}

// ---------------- Kernel 3: y = LN(ao @ Wo^T + bo + x) ----------------
template<bool F32> DEV void k_out_body(const unsigned short* __restrict__ ao,
                                       const void* __restrict__ Wo, const void* __restrict__ bo,
                                       const void* __restrict__ x, const void* __restrict__ gamma,
                                       const void* __restrict__ beta, void* __restrict__ out,
                                       float (&y_s)[16][132]) {
  const int tid = threadIdx.x, lane = tid & 63, wave = tid >> 6;
  const int m = lane & 15, q = lane >> 4;
  const int rbase = blockIdx.x * 16;
  bf16x8 af[4];
#pragma unroll
  for (int k = 0; k < 4; ++k)
    af[k] = ldfrag<false>(ao, ((size_t)(rbase + m)) * 128 + q * 8 + k * 32);
  f32x4 acc[2] = {{0.f,0.f,0.f,0.f},{0.f,0.f,0.f,0.f}};
#pragma unroll
  for (int ct = 0; ct < 2; ++ct) {
    const size_t wrow = (size_t)(wave * 32 + ct * 16 + m) * 128 + q * 8;
#pragma unroll
    for (int k = 0; k < 4; ++k)
      acc[ct] = __builtin_amdgcn_mfma_f32_16x16x32_bf16(af[k], ldfrag<F32>(Wo, wrow + k * 32),
                                                        acc[ct], 0, 0, 0);
  }
#pragma unroll
  for (int ct = 0; ct < 2; ++ct) {
    const int c = wave * 32 + ct * 16 + m;
    const float bov = ldS<F32>(bo, c);
#pragma unroll
    for (int r = 0; r < 4; ++r) {
      const int row = q * 4 + r;
      y_s[row][c] = acc[ct][r] + bov + ldS<F32>(x, (size_t)(rbase + row) * 128 + c);
    }
  }
  __syncthreads();
  const int r = tid >> 4, c16 = tid & 15;
  float vals[8], sum = 0.f, sq = 0.f;
#pragma unroll
  for (int k = 0; k < 8; ++k) {
    const float v = y_s[r][c16 * 8 + k];
    vals[k] = v; sum += v; sq += v * v;
  }
#pragma unroll
  for (int msk = 1; msk < 16; msk <<= 1) {
    sum += __shfl_xor(sum, msk, 16);
    sq  += __shfl_xor(sq,  msk, 16);
  }
  const float mu  = sum * (1.f / 128.f);
  const float var = fmaxf(sq * (1.f / 128.f) - mu * mu, 0.f);
  const float rstd = rsqrtf(var + 1e-5f);
  float o[8];
#pragma unroll
  for (int k = 0; k < 8; ++k) {
    const int c = c16 * 8 + k;
    o[k] = (vals[k] - mu) * rstd * ldS<F32>(gamma, c) + ldS<F32>(beta, c);
  }
  const size_t obase = (size_t)(rbase + r) * 128 + c16 * 8;
  if constexpr (F32) {
    float* op = (float*)out + obase;
    f32x4 w0 = {o[0],o[1],o[2],o[3]}, w1 = {o[4],o[5],o[6],o[7]};
    *(f32x4*)op = w0; *(f32x4*)(op + 4) = w1;
  } else {
    union { unsigned short u[8]; i32x4 v; } ob;
#pragma unroll
    for (int k = 0; k < 8; ++k) ob.u[k] = f_to_bf(o[k]);
    *(i32x4*)((unsigned short*)out + obase) = ob.v;
  }
}
__global__ __launch_bounds__(256) void k_out(const unsigned short* ao, const void* Wo,
                                             const void* bo, const void* x, const void* gamma,
                                             const void* beta, void* out, const void* adj) {
  __shared__ __align__(16) float y_s[16][132];   // shared across both instantiations
  if (detect_f32(adj)) k_out_body<true>(ao, Wo, bo, x, gamma, beta, out, y_s);
  else                 k_out_body<false>(ao, Wo, bo, x, gamma, beta, out, y_s);
}

// ---------------- launch ----------------
extern "C" void kernel_launch(void* const* d_in, const int* in_sizes, int n_in,
                              void* d_out, int out_size, void* d_ws, size_t ws_size,
                              hipStream_t stream) {
  const void* x     = d_in[0];
  const void* adj   = d_in[1];
  const void* W     = d_in[2];
  const void* a_src = d_in[3];
  const void* a_dst = d_in[4];
  const void* Wo    = d_in[5];
  const void* bo    = d_in[6];
  const void* gamma = d_in[7];
  const void* beta  = d_in[8];

  char* ws = (char*)d_ws;
  unsigned char*  hT_ws  = (unsigned char*)ws;               // 2,097,152 B  fp8 hT (BH*32, N)
  unsigned short* ao_ws  = (unsigned short*)(ws + 2097152);  // 4,194,304 B  bf16 attn out
  float*          rv_ws  = (float*)(ws + 6291456);           // 262,144 B    fp32 R=exp(-.8 src)
  unsigned int*   fh_ws  = (unsigned int*)(ws + 6553600);    // 262,144 B    packed bf16 F,H
  unsigned char*  adjf   = (unsigned char*)(ws + 6815744);   // 4,194,304 B  fp8 adj
                                                             // total 11,010,048 B

  k_prep<<<2048, 256, 0, stream>>>(adj, adjf);
  k_h   <<<1024, 256, 0, stream>>>(x, W, hT_ws, adj);
  k_sd  <<<256,  256, 0, stream>>>(hT_ws, a_src, a_dst, rv_ws, fh_ws, adj);
  k_attn<<<512,  256, 0, stream>>>(adjf, hT_ws, rv_ws, fh_ws, ao_ws);
  k_out <<<1024, 256, 0, stream>>>(ao_ws, Wo, bo, x, gamma, beta, d_out, adj);
}